// Round 18
// baseline (99.903 us; speedup 1.0000x reference)
//
#include <hip/hip_runtime.h>
#include <hip/hip_bf16.h>

typedef __bf16 bf16x8 __attribute__((ext_vector_type(8)));
typedef float  f32x4  __attribute__((ext_vector_type(4)));

#define MFMA32(acc, a, b) acc = __builtin_amdgcn_mfma_f32_16x16x32_bf16(a, b, acc, 0, 0, 0)
#define LD4(p) (*(const float4*)(p))

__device__ __forceinline__ bf16x8 cvt8(float4 a, float4 b) {
  bf16x8 r;
  r[0] = (__bf16)a.x; r[1] = (__bf16)a.y; r[2] = (__bf16)a.z; r[3] = (__bf16)a.w;
  r[4] = (__bf16)b.x; r[5] = (__bf16)b.y; r[6] = (__bf16)b.z; r[7] = (__bf16)b.w;
  return r;
}

// DPP helpers: row_ror:N = 0x120|N (16-lane rotate), quad_perm xor2=0x4E, xor1=0xB1.
template <int CTRL>
__device__ __forceinline__ float dpp_mov(float x) {
  int yi = __builtin_amdgcn_update_dpp(0, __builtin_bit_cast(int, x), CTRL, 0xF, 0xF, true);
  return __builtin_bit_cast(float, yi);
}
template <int CTRL>
__device__ __forceinline__ float dpp_fadd(float x) { return x + dpp_mov<CTRL>(x); }

// Packed 16-reg cross-16-lane reduce (validated R6-R17): lane lr ends with the
// full 16-lane sum of o[lr]; dim(l) = (lr>>3)*32 + g*8 + (lr&7).
__device__ __forceinline__ float tree16(const float* o, int lr) {
  float q8[8];
#pragma unroll
  for (int t = 0; t < 8; t++) {
    const bool up = (lr & 8);
    float sel = up ? o[t + 8] : o[t];
    float oth = up ? o[t] : o[t + 8];
    q8[t] = sel + dpp_mov<0x128>(oth);
  }
  float q4[4];
#pragma unroll
  for (int t = 0; t < 4; t++) {
    const bool up = (lr & 4);
    float sel = up ? q8[t + 4] : q8[t];
    float oth = up ? q8[t] : q8[t + 4];
    q4[t] = sel + __shfl_xor(oth, 4);
  }
  float q2[2];
#pragma unroll
  for (int t = 0; t < 2; t++) {
    const bool up = (lr & 2);
    float sel = up ? q4[t + 2] : q4[t];
    float oth = up ? q4[t] : q4[t + 2];
    q2[t] = sel + dpp_mov<0x4E>(oth);
  }
  const bool up = (lr & 1);
  float sel = up ? q2[1] : q2[0];
  float oth = up ? q2[0] : q2[1];
  return sel + dpp_mov<0xB1>(oth);
}

// W1frag [ks=4][mt=4][lane][j=8] = W1[ks*32+(lane>>4)*8+j][mt*16+(lane&15)]
// W2frag [ks2=2][mt2=4][lane][j=8] = W2[rho][mt2*16+(lane&15)],
//   rho(ks2,g,j) = (ks2*2+(j>>2))*16 + g*4 + (j&3) — matches in-register hb layout.
__global__ void prep_frags(const float* __restrict__ W1,
                           const float* __restrict__ W2,
                           __bf16* __restrict__ wf) {
  int idx = blockIdx.x * 256 + threadIdx.x;
  if (idx < 8192) {
    int j = idx & 7, lane = (idx >> 3) & 63, mt = (idx >> 9) & 3, ks = idx >> 11;
    int i = ks * 32 + ((lane >> 4) << 3) + j;
    int col = mt * 16 + (lane & 15);
    wf[idx] = (__bf16)W1[i * 64 + col];
  } else if (idx < 12288) {
    int t = idx - 8192;
    int j = t & 7, lane = (t >> 3) & 63, mt2 = (t >> 9) & 3, ks2 = (t >> 11) & 1;
    int g = (lane >> 4) & 3;
    int rho = (ks2 * 2 + (j >> 2)) * 16 + g * 4 + (j & 3);
    wf[idx] = (__bf16)W2[rho * 64 + mt2 * 16 + (lane & 15)];
  }
}

// LIGHT kernel: deg 0..16 only (single-tile MLP; ~49% of nodes + deg-0).
// Register thesis (R2-R17 ladder): single-tile path needs acc[4]=16 AGPR +
// 2 ef frags + no i1/m1/sv1 state -> total ~60 <= 64 -> 8 waves/SIMD, ~2x
// the occupancy of the dual-tile kernel. Heavy nodes are skipped in ~20 cy.
// LDS: [0,16384) W1frag  [16384,24576) W2frag
//      [24576,24832) b1  [24832,25088) b2  [25088,25344) w3
__global__ __launch_bounds__(512) void agg_light(
    const float* __restrict__ emb,
    const float* __restrict__ b1g, const float* __restrict__ b2g,
    const float* __restrict__ w3g,
    const int* __restrict__ vn, const int* __restrict__ ni,
    const int* __restrict__ nd,
    const __bf16* __restrict__ wf,
    float* __restrict__ out, int N) {
  __shared__ __align__(16) unsigned char smem[25344];
  {
    const uint4* src = (const uint4*)wf;
    uint4* dst = (uint4*)smem;
#pragma unroll
    for (int i = 0; i < 3; i++) dst[threadIdx.x + i * 512] = src[threadIdx.x + i * 512];
    int t = threadIdx.x;
    if (t < 64) {
      ((float*)(smem + 24576))[t] = b1g[t];
      ((float*)(smem + 24832))[t] = b2g[t];
      ((float*)(smem + 25088))[t] = w3g[t];
    }
  }
  __syncthreads();

  const __bf16* w1f = (const __bf16*)smem;
  const __bf16* w2f = (const __bf16*)(smem + 16384);
  const int wid = threadIdx.x >> 6;
  const int l   = threadIdx.x & 63;
  const int g   = l >> 4;
  const int lr  = l & 15;

  const int gw = blockIdx.x * 8 + wid;
  const int nwaves = gridDim.x * 8;

  int n = gw;
  int node = 0, deg = 0, i0 = 0;
  if (n < N) {
    node = vn[n]; deg = nd[n];
    i0 = (deg <= 16) ? ni[(long)n * 32 + lr] : 0;   // wave-uniform cond
  }

  for (; n < N; n += nwaves) {
    const int cn = node, cd = deg, ci0 = i0;
    {
      int nn = n + nwaves; if (nn >= N) nn = n;
      node = vn[nn]; deg = nd[nn];
      i0 = (deg <= 16) ? ni[(long)nn * 32 + lr] : 0;
    }
    if (cd > 16) continue;                       // heavy kernel's node

    const float* ub = emb + (long)cn * 64;
    if (cd == 0) {                               // copy own embedding (exact)
      out[(long)n * 64 + l] = ub[l];
      continue;
    }

    int boff = 24576;
    asm volatile("" : "+v"(boff));   // opaque: keep bias reads in LDS, not regs
    const unsigned char* bb = smem + boff;

    // ---- gather own 16 rows (clamp pad lanes to center) + center row ----
    bf16x8 ef0, ef1, uf0, uf1;
    {
      const int a = (lr < cd) ? ci0 : cn;
      const float* p = emb + (long)a * 64 + g * 8;
      ef0 = cvt8(LD4(p), LD4(p + 4));
      ef1 = cvt8(LD4(p + 32), LD4(p + 36));
      const float* q = ub + g * 8;
      uf0 = cvt8(LD4(q), LD4(q + 4));
      uf1 = cvt8(LD4(q + 32), LD4(q + 36));
    }

    // ---- layer 1 (single tile): acc init = b1 ----
    f32x4 acc[4];
#pragma unroll
    for (int mt = 0; mt < 4; mt++)
      acc[mt] = *(const f32x4*)(bb + (mt * 16 + g * 4) * 4);
    const bf16x8 xs[4] = {ef0, ef1, uf0, uf1};
#pragma unroll
    for (int ks = 0; ks < 4; ks++)
#pragma unroll
      for (int mt = 0; mt < 4; mt++) {
        bf16x8 wa = *(const bf16x8*)(w1f + ((ks * 4 + mt) * 64 + l) * 8);
        MFMA32(acc[mt], wa, xs[ks]);
      }

    // ---- relu -> layer-2 B-frags (permuted k-axis) ----
    bf16x8 hb[2];
#pragma unroll
    for (int ks2 = 0; ks2 < 2; ks2++) {
      bf16x8 v;
#pragma unroll
      for (int j = 0; j < 8; j++) {
        const int mt = ks2 * 2 + (j >> 2), r = j & 3;
        v[j] = (__bf16)fmaxf(acc[mt][r], 0.f);
      }
      hb[ks2] = v;
    }

    // ---- layer 2: REUSE acc ----
#pragma unroll
    for (int mt2 = 0; mt2 < 4; mt2++)
      acc[mt2] = *(const f32x4*)(bb + 256 + (mt2 * 16 + g * 4) * 4);
#pragma unroll
    for (int ks2 = 0; ks2 < 2; ks2++)
#pragma unroll
      for (int mt2 = 0; mt2 < 4; mt2++) {
        bf16x8 wa = *(const bf16x8*)(w2f + ((ks2 * 4 + mt2) * 64 + l) * 8);
        MFMA32(acc[mt2], wa, hb[ks2]);
      }

    // ---- scores (b3 cancels) ----
    float sv = 0.f;
#pragma unroll
    for (int mt2 = 0; mt2 < 4; mt2++) {
      f32x4 wv = *(const f32x4*)(bb + 512 + (mt2 * 16 + g * 4) * 4);
#pragma unroll
      for (int r = 0; r < 4; r++)
        sv += fmaxf(acc[mt2][r], 0.f) * wv[r];
    }
    sv += __shfl_xor(sv, 16);
    sv += __shfl_xor(sv, 32);

    // ---- no-max softmax over 16 (validated R14-R17) ----
    const float p0 = (lr < cd) ? __expf(sv) : 0.f;
    float sum = p0;
    sum = dpp_fadd<0x128>(sum);
    sum = dpp_fadd<0x124>(sum);
    sum = dpp_fadd<0x122>(sum);
    sum = dpp_fadd<0x121>(sum);
    const float a0 = p0 / sum;

    // ---- einsum + packed tree + coalesced store ----
    float o[16];
#pragma unroll
    for (int j = 0; j < 8; j++) {
      o[j]     = a0 * (float)ef0[j];
      o[8 + j] = a0 * (float)ef1[j];
    }
    const int dim = ((lr >> 3) << 5) + g * 8 + (lr & 7);
    out[(long)n * 64 + dim] = tree16(o, lr);
  }
}

// HEAVY kernel: deg 17..32 only. R16 body with all m1 branches deleted
// (both tiles unconditionally live). Light nodes skipped in ~20 cy.
__global__ __launch_bounds__(512) void agg_heavy(
    const float* __restrict__ emb,
    const float* __restrict__ b1g, const float* __restrict__ b2g,
    const float* __restrict__ w3g,
    const int* __restrict__ vn, const int* __restrict__ ni,
    const int* __restrict__ nd,
    const __bf16* __restrict__ wf,
    float* __restrict__ out, int N) {
  __shared__ __align__(16) unsigned char smem[25344];
  {
    const uint4* src = (const uint4*)wf;
    uint4* dst = (uint4*)smem;
#pragma unroll
    for (int i = 0; i < 3; i++) dst[threadIdx.x + i * 512] = src[threadIdx.x + i * 512];
    int t = threadIdx.x;
    if (t < 64) {
      ((float*)(smem + 24576))[t] = b1g[t];
      ((float*)(smem + 24832))[t] = b2g[t];
      ((float*)(smem + 25088))[t] = w3g[t];
    }
  }
  __syncthreads();

  const __bf16* w1f = (const __bf16*)smem;
  const __bf16* w2f = (const __bf16*)(smem + 16384);
  const int wid = threadIdx.x >> 6;
  const int l   = threadIdx.x & 63;
  const int g   = l >> 4;
  const int lr  = l & 15;

  const int gw = blockIdx.x * 8 + wid;
  const int nwaves = gridDim.x * 8;

  int n = gw;
  int node = 0, deg = 0, i0 = 0, i1 = 0;
  if (n < N) {
    node = vn[n]; deg = nd[n];
    const bool h = (deg > 16);                   // wave-uniform cond
    i0 = h ? ni[(long)n * 32 + lr] : 0;
    i1 = h ? ni[(long)n * 32 + 16 + lr] : 0;
  }

  for (; n < N; n += nwaves) {
    const int cn = node, cd = deg, ci0 = i0, ci1 = i1;
    {
      int nn = n + nwaves; if (nn >= N) nn = n;
      node = vn[nn]; deg = nd[nn];
      const bool h = (deg > 16);
      i0 = h ? ni[(long)nn * 32 + lr] : 0;
      i1 = h ? ni[(long)nn * 32 + 16 + lr] : 0;
    }
    if (cd <= 16) continue;                      // light kernel's node

    const float* ub = emb + (long)cn * 64;

    int boff = 24576;
    asm volatile("" : "+v"(boff));
    const unsigned char* bb = smem + boff;

    // ---- gather both tiles (clamp pad lanes to center) ----
    bf16x8 ef00, ef01, ef10, ef11, uf0, uf1;
    {
      const float* p = emb + (long)ci0 * 64 + g * 8;   // rows 0..15 < cd always
      ef00 = cvt8(LD4(p), LD4(p + 4));
      ef01 = cvt8(LD4(p + 32), LD4(p + 36));
    }
    {
      const int a = (16 + lr < cd) ? ci1 : cn;
      const float* p = emb + (long)a * 64 + g * 8;
      ef10 = cvt8(LD4(p), LD4(p + 4));
      ef11 = cvt8(LD4(p + 32), LD4(p + 36));
    }
    {
      const float* q = ub + g * 8;
      uf0 = cvt8(LD4(q), LD4(q + 4));
      uf1 = cvt8(LD4(q + 32), LD4(q + 36));
    }

    // ---- layer 1 ----
    f32x4 acc[4][2];
#pragma unroll
    for (int mt = 0; mt < 4; mt++) {
      f32x4 bv = *(const f32x4*)(bb + (mt * 16 + g * 4) * 4);
      acc[mt][0] = bv; acc[mt][1] = bv;
    }
    const bf16x8 xb0s[4] = {ef00, ef01, uf0, uf1};
    const bf16x8 xb1s[4] = {ef10, ef11, uf0, uf1};
#pragma unroll
    for (int ks = 0; ks < 4; ks++)
#pragma unroll
      for (int mt = 0; mt < 4; mt++) {
        bf16x8 wa = *(const bf16x8*)(w1f + ((ks * 4 + mt) * 64 + l) * 8);
        MFMA32(acc[mt][0], wa, xb0s[ks]);
        MFMA32(acc[mt][1], wa, xb1s[ks]);
      }

    // ---- relu -> layer-2 B-frags ----
    bf16x8 hb[2][2];
#pragma unroll
    for (int ks2 = 0; ks2 < 2; ks2++)
#pragma unroll
      for (int nt = 0; nt < 2; nt++) {
        bf16x8 v;
#pragma unroll
        for (int j = 0; j < 8; j++) {
          const int mt = ks2 * 2 + (j >> 2), r = j & 3;
          v[j] = (__bf16)fmaxf(acc[mt][nt][r], 0.f);
        }
        hb[ks2][nt] = v;
      }

    // ---- layer 2: REUSE acc ----
#pragma unroll
    for (int mt2 = 0; mt2 < 4; mt2++) {
      f32x4 bv = *(const f32x4*)(bb + 256 + (mt2 * 16 + g * 4) * 4);
      acc[mt2][0] = bv; acc[mt2][1] = bv;
    }
#pragma unroll
    for (int ks2 = 0; ks2 < 2; ks2++)
#pragma unroll
      for (int mt2 = 0; mt2 < 4; mt2++) {
        bf16x8 wa = *(const bf16x8*)(w2f + ((ks2 * 4 + mt2) * 64 + l) * 8);
        MFMA32(acc[mt2][0], wa, hb[ks2][0]);
        MFMA32(acc[mt2][1], wa, hb[ks2][1]);
      }

    // ---- scores (b3 cancels) ----
    float sv0 = 0.f, sv1 = 0.f;
#pragma unroll
    for (int mt2 = 0; mt2 < 4; mt2++) {
      f32x4 wv = *(const f32x4*)(bb + 512 + (mt2 * 16 + g * 4) * 4);
#pragma unroll
      for (int r = 0; r < 4; r++) {
        sv0 += fmaxf(acc[mt2][0][r], 0.f) * wv[r];
        sv1 += fmaxf(acc[mt2][1][r], 0.f) * wv[r];
      }
    }
    sv0 += __shfl_xor(sv0, 16); sv0 += __shfl_xor(sv0, 32);
    sv1 += __shfl_xor(sv1, 16); sv1 += __shfl_xor(sv1, 32);

    // ---- no-max softmax over 32 ----
    const bool v1 = (16 + lr < cd);
    const float p0 = __expf(sv0);                 // rows 0..15 always valid
    const float p1 = v1 ? __expf(sv1) : 0.f;
    float sum = p0 + p1;
    sum = dpp_fadd<0x128>(sum);
    sum = dpp_fadd<0x124>(sum);
    sum = dpp_fadd<0x122>(sum);
    sum = dpp_fadd<0x121>(sum);
    const float inv = 1.f / sum;
    const float a0 = p0 * inv, a1 = p1 * inv;

    // ---- einsum + packed tree + coalesced store ----
    float o[16];
#pragma unroll
    for (int j = 0; j < 8; j++) {
      o[j]     = a0 * (float)ef00[j] + a1 * (float)ef10[j];
      o[8 + j] = a0 * (float)ef01[j] + a1 * (float)ef11[j];
    }
    const int dim = ((lr >> 3) << 5) + g * 8 + (lr & 7);
    out[(long)n * 64 + dim] = tree16(o, lr);
  }
}

extern "C" void kernel_launch(void* const* d_in, const int* in_sizes, int n_in,
                              void* d_out, int out_size, void* d_ws, size_t ws_size,
                              hipStream_t stream) {
  const float* emb = (const float*)d_in[0];
  const float* W1  = (const float*)d_in[1];
  const float* b1  = (const float*)d_in[2];
  const float* W2  = (const float*)d_in[3];
  const float* b2  = (const float*)d_in[4];
  const float* w3  = (const float*)d_in[5];
  const int* vn = (const int*)d_in[7];
  const int* ni = (const int*)d_in[8];
  const int* nd = (const int*)d_in[9];
  float* out = (float*)d_out;
  const int N = in_sizes[7];
  __bf16* wf = (__bf16*)d_ws;   // 24576 B

  prep_frags<<<48, 256, 0, stream>>>(W1, W2, wf);
  agg_light<<<2048, 512, 0, stream>>>(emb, b1, b2, w3, vn, ni, nd, wf, out, N);
  agg_heavy<<<2048, 512, 0, stream>>>(emb, b1, b2, w3, vn, ni, nd, wf, out, N);
}

// Round 19
// 74.630 us; speedup vs baseline: 1.3386x; 1.3386x over previous
//
#include <hip/hip_runtime.h>
#include <hip/hip_bf16.h>

typedef __bf16 bf16x8 __attribute__((ext_vector_type(8)));
typedef float  f32x4  __attribute__((ext_vector_type(4)));

#define MFMA32(acc, a, b) acc = __builtin_amdgcn_mfma_f32_16x16x32_bf16(a, b, acc, 0, 0, 0)
#define LD4(p) (*(const float4*)(p))

__device__ __forceinline__ bf16x8 cvt8(float4 a, float4 b) {
  bf16x8 r;
  r[0] = (__bf16)a.x; r[1] = (__bf16)a.y; r[2] = (__bf16)a.z; r[3] = (__bf16)a.w;
  r[4] = (__bf16)b.x; r[5] = (__bf16)b.y; r[6] = (__bf16)b.z; r[7] = (__bf16)b.w;
  return r;
}

// DPP helpers: row_ror:N = 0x120|N (16-lane rotate), quad_perm xor2=0x4E, xor1=0xB1.
template <int CTRL>
__device__ __forceinline__ float dpp_mov(float x) {
  int yi = __builtin_amdgcn_update_dpp(0, __builtin_bit_cast(int, x), CTRL, 0xF, 0xF, true);
  return __builtin_bit_cast(float, yi);
}
template <int CTRL>
__device__ __forceinline__ float dpp_fadd(float x) { return x + dpp_mov<CTRL>(x); }

// Packed 16-reg cross-16-lane reduce (validated R6-R18): lane lr ends with the
// full 16-lane sum of o[lr]; dim(l) = (lr>>3)*32 + g*8 + (lr&7).
__device__ __forceinline__ float tree16(const float* o, int lr) {
  float q8[8];
#pragma unroll
  for (int t = 0; t < 8; t++) {
    const bool up = (lr & 8);
    float sel = up ? o[t + 8] : o[t];
    float oth = up ? o[t] : o[t + 8];
    q8[t] = sel + dpp_mov<0x128>(oth);
  }
  float q4[4];
#pragma unroll
  for (int t = 0; t < 4; t++) {
    const bool up = (lr & 4);
    float sel = up ? q8[t + 4] : q8[t];
    float oth = up ? q8[t] : q8[t + 4];
    q4[t] = sel + __shfl_xor(oth, 4);
  }
  float q2[2];
#pragma unroll
  for (int t = 0; t < 2; t++) {
    const bool up = (lr & 2);
    float sel = up ? q4[t + 2] : q4[t];
    float oth = up ? q4[t] : q4[t + 2];
    q2[t] = sel + dpp_mov<0x4E>(oth);
  }
  const bool up = (lr & 1);
  float sel = up ? q2[1] : q2[0];
  float oth = up ? q2[0] : q2[1];
  return sel + dpp_mov<0xB1>(oth);
}

// W1frag [ks=4][mt=4][lane][j=8] = W1[ks*32+(lane>>4)*8+j][mt*16+(lane&15)]
// W2frag [ks2=2][mt2=4][lane][j=8] = W2[rho][mt2*16+(lane&15)],
//   rho(ks2,g,j) = (ks2*2+(j>>2))*16 + g*4 + (j&3) — matches in-register hb layout.
__global__ void prep_frags(const float* __restrict__ W1,
                           const float* __restrict__ W2,
                           __bf16* __restrict__ wf) {
  int idx = blockIdx.x * 256 + threadIdx.x;
  if (idx < 8192) {
    int j = idx & 7, lane = (idx >> 3) & 63, mt = (idx >> 9) & 3, ks = idx >> 11;
    int i = ks * 32 + ((lane >> 4) << 3) + j;
    int col = mt * 16 + (lane & 15);
    wf[idx] = (__bf16)W1[i * 64 + col];
  } else if (idx < 12288) {
    int t = idx - 8192;
    int j = t & 7, lane = (t >> 3) & 63, mt2 = (t >> 9) & 3, ks2 = (t >> 11) & 1;
    int g = (lane >> 4) & 3;
    int rho = (ks2 * 2 + (j >> 2)) * 16 + g * 4 + (j & 3);
    wf[idx] = (__bf16)W2[rho * 64 + mt2 * 16 + (lane & 15)];
  }
}

// FINAL (R16 = best measured, 74.2 us): one wave per node, grid-stride,
// 512 thr = 8 waves/block, grid 2048. Techniques, each validated by A/B over
// R1-R18: transposed in-register MLP (W^T A-frags from LDS, layer-2 B-frags
// = permuted layer-1 accs, zero H1 LDS round-trip); descriptor prefetch one
// iteration ahead; clamp-gather (pad lanes read center row, masked to p=0);
// single reused acc[4][2] array; no-max softmax (scores bounded, exact-ish)
// with b3 cancelled; DPP-packed output reduce + all-64-lane coalesced store.
// Structural constraint (documented R2-R18): working set ~88 unified V+A regs
// pins residency; every latency-hiding construct (reg prefetch, async DMA,
// cache-warm, kernel split) inflates live ranges past the 64-reg/4-wave
// cliff and loses >= its gain. No launch-bounds min (R3/R4: forces spill or
// rematerialization).
// LDS: [0,16384) W1frag  [16384,24576) W2frag
//      [24576,24832) b1  [24832,25088) b2  [25088,25344) w3
__global__ __launch_bounds__(512) void graph_agg(
    const float* __restrict__ emb,
    const float* __restrict__ b1g, const float* __restrict__ b2g,
    const float* __restrict__ w3g,
    const int* __restrict__ vn, const int* __restrict__ ni,
    const int* __restrict__ nd,
    const __bf16* __restrict__ wf,
    float* __restrict__ out, int N) {
  __shared__ __align__(16) unsigned char smem[25344];

  {
    const uint4* src = (const uint4*)wf;
    uint4* dst = (uint4*)smem;
#pragma unroll
    for (int i = 0; i < 3; i++) dst[threadIdx.x + i * 512] = src[threadIdx.x + i * 512];
    int t = threadIdx.x;
    if (t < 64) {
      ((float*)(smem + 24576))[t] = b1g[t];
      ((float*)(smem + 24832))[t] = b2g[t];
      ((float*)(smem + 25088))[t] = w3g[t];
    }
  }
  __syncthreads();

  const __bf16* w1f = (const __bf16*)smem;
  const __bf16* w2f = (const __bf16*)(smem + 16384);
  const int wid = threadIdx.x >> 6;
  const int l   = threadIdx.x & 63;
  const int g   = l >> 4;
  const int lr  = l & 15;

  const int gw = blockIdx.x * 8 + wid;
  const int nwaves = gridDim.x * 8;

  int n = gw;
  int node = 0, deg = 0, i0 = 0, i1 = 0;
  if (n < N) {
    node = vn[n]; deg = nd[n];
    i0 = ni[(long)n * 32 + lr]; i1 = ni[(long)n * 32 + 16 + lr];
  }

  for (; n < N; n += nwaves) {
    const int cn = node, cd = deg, ci0 = i0, ci1 = i1;
    {  // prefetch next iteration's descriptor
      int nn = n + nwaves; if (nn >= N) nn = n;
      node = vn[nn]; deg = nd[nn];
      i0 = ni[(long)nn * 32 + lr]; i1 = ni[(long)nn * 32 + 16 + lr];
    }
    const float* ub = emb + (long)cn * 64;

    if (cd == 0) {                 // no neighbors: copy own embedding (exact)
      out[(long)n * 64 + l] = ub[l];
      continue;
    }
    const bool m1 = (cd > 16);

    int boff = 24576;
    asm volatile("" : "+v"(boff));   // opaque: keep bias reads in LDS, not regs
    const unsigned char* bb = smem + boff;

    // ---- gather (clamp pad lanes to center row; their scores yield p=0 via
    //      the validity select, so garbage cannot propagate) ----
    bf16x8 ef00, ef01, ef10, ef11;
    {
      const int a = (lr < cd) ? ci0 : cn;
      const float* p = emb + (long)a * 64 + g * 8;
      ef00 = cvt8(LD4(p), LD4(p + 4));
      ef01 = cvt8(LD4(p + 32), LD4(p + 36));
    }
    if (m1) {
      const int a = (16 + lr < cd) ? ci1 : cn;
      const float* p = emb + (long)a * 64 + g * 8;
      ef10 = cvt8(LD4(p), LD4(p + 4));
      ef11 = cvt8(LD4(p + 32), LD4(p + 36));
    }
    bf16x8 uf0, uf1;
    {
      const float* q = ub + g * 8;
      uf0 = cvt8(LD4(q), LD4(q + 4));
      uf1 = cvt8(LD4(q + 32), LD4(q + 36));
    }

    // ---- layer 1: C1t[64][32] = W1^T @ [E|u]^T (acc init = b1) ----
    f32x4 acc[4][2];
#pragma unroll
    for (int mt = 0; mt < 4; mt++) {
      f32x4 bv = *(const f32x4*)(bb + (mt * 16 + g * 4) * 4);
      acc[mt][0] = bv; acc[mt][1] = bv;
    }
    const bf16x8 xb0s[4] = {ef00, ef01, uf0, uf1};
    const bf16x8 xb1s[4] = {ef10, ef11, uf0, uf1};
#pragma unroll
    for (int ks = 0; ks < 4; ks++) {
#pragma unroll
      for (int mt = 0; mt < 4; mt++) {
        bf16x8 wa = *(const bf16x8*)(w1f + ((ks * 4 + mt) * 64 + l) * 8);
        MFMA32(acc[mt][0], wa, xb0s[ks]);
        if (m1) MFMA32(acc[mt][1], wa, xb1s[ks]);
      }
    }

    // ---- relu -> layer-2 B-frags (permuted k-axis, in-register) ----
    bf16x8 hb[2][2];
#pragma unroll
    for (int ks2 = 0; ks2 < 2; ks2++)
#pragma unroll
      for (int nt = 0; nt < 2; nt++) {
        if (nt == 0 || m1) {
          bf16x8 v;
#pragma unroll
          for (int j = 0; j < 8; j++) {
            const int mt = ks2 * 2 + (j >> 2), r = j & 3;
            v[j] = (__bf16)fmaxf(acc[mt][nt][r], 0.f);
          }
          hb[ks2][nt] = v;
        }
      }

    // ---- layer 2: REUSE acc ----
#pragma unroll
    for (int mt2 = 0; mt2 < 4; mt2++) {
      f32x4 bv = *(const f32x4*)(bb + 256 + (mt2 * 16 + g * 4) * 4);
      acc[mt2][0] = bv; acc[mt2][1] = bv;
    }
#pragma unroll
    for (int ks2 = 0; ks2 < 2; ks2++)
#pragma unroll
      for (int mt2 = 0; mt2 < 4; mt2++) {
        bf16x8 wa = *(const bf16x8*)(w2f + ((ks2 * 4 + mt2) * 64 + l) * 8);
        MFMA32(acc[mt2][0], wa, hb[ks2][0]);
        if (m1) MFMA32(acc[mt2][1], wa, hb[ks2][1]);
      }

    // ---- scores: s[nb] = relu(C2t+b2) . w3  (b3 cancels in softmax) ----
    float sv0 = 0.f, sv1 = 0.f;
#pragma unroll
    for (int mt2 = 0; mt2 < 4; mt2++) {
      f32x4 wv = *(const f32x4*)(bb + 512 + (mt2 * 16 + g * 4) * 4);
#pragma unroll
      for (int r = 0; r < 4; r++) {
        sv0 += fmaxf(acc[mt2][0][r], 0.f) * wv[r];
        if (m1) sv1 += fmaxf(acc[mt2][1][r], 0.f) * wv[r];
      }
    }
    sv0 += __shfl_xor(sv0, 16); sv0 += __shfl_xor(sv0, 32);
    if (m1) { sv1 += __shfl_xor(sv1, 16); sv1 += __shfl_xor(sv1, 32); }

    // ---- no-max softmax (validated R14-R18: |s| bounded, masked lanes p=0)
    const bool v0 = (lr < cd);
    const bool v1 = m1 && (16 + lr < cd);
    float p0 = v0 ? __expf(sv0) : 0.f;
    float p1 = v1 ? __expf(sv1) : 0.f;
    float sum = p0 + p1;
    sum = dpp_fadd<0x128>(sum);
    sum = dpp_fadd<0x124>(sum);
    sum = dpp_fadd<0x122>(sum);
    sum = dpp_fadd<0x121>(sum);
    const float inv = 1.f / sum;
    const float a0 = p0 * inv, a1 = p1 * inv;

    // ---- out[d] = sum_k att[k]*e[k][d]: packed tree, all-lane coalesced store
    float o[16];
#pragma unroll
    for (int j = 0; j < 8; j++) {
      float v = a0 * (float)ef00[j];
      if (m1) v += a1 * (float)ef10[j];
      o[j] = v;
      float w = a0 * (float)ef01[j];
      if (m1) w += a1 * (float)ef11[j];
      o[8 + j] = w;
    }
    const int dim = ((lr >> 3) << 5) + g * 8 + (lr & 7);
    out[(long)n * 64 + dim] = tree16(o, lr);
  }
}

extern "C" void kernel_launch(void* const* d_in, const int* in_sizes, int n_in,
                              void* d_out, int out_size, void* d_ws, size_t ws_size,
                              hipStream_t stream) {
  const float* emb = (const float*)d_in[0];
  const float* W1  = (const float*)d_in[1];
  const float* b1  = (const float*)d_in[2];
  const float* W2  = (const float*)d_in[3];
  const float* b2  = (const float*)d_in[4];
  const float* w3  = (const float*)d_in[5];
  const int* vn = (const int*)d_in[7];
  const int* ni = (const int*)d_in[8];
  const int* nd = (const int*)d_in[9];
  float* out = (float*)d_out;
  const int N = in_sizes[7];
  __bf16* wf = (__bf16*)d_ws;   // 24576 B

  prep_frags<<<48, 256, 0, stream>>>(W1, W2, wf);
  graph_agg<<<2048, 512, 0, stream>>>(emb, b1, b2, w3, vn, ni, nd, wf, out, N);
}